// Round 12
// baseline (207.422 us; speedup 1.0000x reference)
//
#include <hip/hip_runtime.h>

typedef unsigned short u16;
typedef unsigned int   u32;
typedef __attribute__((ext_vector_type(4))) float f32x4;
typedef __attribute__((ext_vector_type(8))) short s16x8;
typedef __attribute__((ext_vector_type(4))) unsigned short u16x4;
typedef __attribute__((ext_vector_type(8))) unsigned short u16x8;

#define HW    36864
#define NCH   256
#define NB    4
#define NPIX  147456
#define POS   85
#define BN_EPS 1e-5f

// ---- workspace float offsets ----
#define WS_PALL    0            // 4*256*85
#define WS_YD      87040
#define WS_PSUM    174080       // 1024
#define WS_PSQ     175104       // 1024
#define WS_CONTRIB 176128       // 65536 (atomic; zeroed by k_prep)
#define WS_SC      241664       // 256
#define WS_ADD     241920       // 65536
#define WS_WPK     307456       // u16[65536] = 32768 floats
#define WS_PMP     340224       // [b][c][576][4] = 2359296
#define WS_S1P     2699520      // [b][tile][o][8] = 4718592
#define WS_YBF     7418112      // u16 y: 18874368 floats
#define WS_TOT1    26292480

__device__ __forceinline__ u16 f2bf(float f) {
  u32 u = __builtin_bit_cast(u32, f);
  u += 0x7fffu + ((u >> 16) & 1u);
  return (u16)(u >> 16);
}
__device__ __forceinline__ float bf2f(u16 h) {
  u32 u = ((u32)h) << 16;
  return __builtin_bit_cast(float, u);
}

// K0: blocks 0..31: pack wf[:, :256] -> bf16 A-frags; blocks 32..295: zero CONTRIB/PSUM/PSQ
__global__ __launch_bounds__(256) void k_prep(const float* __restrict__ wf, float* __restrict__ wsb) {
  int blk = blockIdx.x, t = threadIdx.x;
  if (blk < 32) {
    int fid = blk*256 + t;                   // [ks32][g][m]
    int m = fid & 255, g = (fid >> 8) & 3, ks = fid >> 10;
    const float* src = wf + (size_t)m*1280 + ks*32 + g*8;
    f32x4 a = *(const f32x4*)src;
    f32x4 c = *(const f32x4*)(src + 4);
    u32* dst = (u32*)((u16*)(wsb + WS_WPK) + (size_t)fid*8);
    dst[0] = (u32)f2bf(a.x) | ((u32)f2bf(a.y) << 16);
    dst[1] = (u32)f2bf(a.z) | ((u32)f2bf(a.w) << 16);
    dst[2] = (u32)f2bf(c.x) | ((u32)f2bf(c.y) << 16);
    dst[3] = (u32)f2bf(c.z) | ((u32)f2bf(c.w) << 16);
    return;
  }
  int id = (blk - 32)*256 + t;               // 0..67583
  if (id < 65536) wsb[WS_CONTRIB + id] = 0.f;
  else { int j = id - 65536; if (j < 2048) wsb[WS_PSUM + j] = 0.f; }
}

// K1: main GEMM (r11 K-loop) + fused non-atomic pooling partials + S1/sumsq partials.
template<bool YBF>
__global__ __launch_bounds__(256, 3) void k_main(const float* __restrict__ x,
                                                 float* __restrict__ wsb, float* __restrict__ y) {
  __shared__ __align__(16) char smem[40960];     // xbuf 20480 | pml 17408 | ytile 36864 (phased)
  u32* xbuf = (u32*)smem;
  int wg = blockIdx.x;
  int b = wg / 576, tile = wg % 576;
  int n0 = tile * 64;
  int t = threadIdx.x, w = t >> 6, l = t & 63, g = l >> 4, ln = l & 15;
  int cb0 = (tile % 3) * 64;
  int cblk0 = cb0 / 24;
  int maxcl = (cb0 + 63)/24 - cblk0;
  const u16* wpk = (const u16*)(wsb + WS_WPK);
  int mrow = w*64 + ln;
  int qq = t & 15, c2 = t >> 4;                  // staging: px-quad, channel-pair
  const float* xsrc = x + (size_t)(b*NCH + 2*c2)*HW + n0 + 4*qq;

  // prologue: x loads for phases 0,1 (slabs 0..3)
  f32x4 xr[2][2][2];                             // [phase parity][slab-in-phase][ch]
  #pragma unroll
  for (int pp = 0; pp < 2; pp++)
    #pragma unroll
    for (int s = 0; s < 2; s++)
      #pragma unroll
      for (int h = 0; h < 2; h++)
        xr[pp][s][h] = *(const f32x4*)(xsrc + (size_t)((pp*2 + s)*32 + h)*HW);

  f32x4 acc[4][4];
  #pragma unroll
  for (int i = 0; i < 4; i++)
    #pragma unroll
    for (int j = 0; j < 4; j++)
      acc[i][j] = {0.f, 0.f, 0.f, 0.f};

  float pmA[8], pmB[8];                          // per-slab quad maxes (raw fp32 x)
  int slot = (((c2 >> 2) ^ (qq & 3)) << 2) | (c2 & 3);   // group-XOR swizzle

  #pragma unroll
  for (int p = 0; p < 4; p++) {
    {
      u32* dst = xbuf + (p & 1)*2560;
      #pragma unroll
      for (int s = 0; s < 2; s++) {
        f32x4 va = xr[p & 1][s][0], vb = xr[p & 1][s][1];
        #pragma unroll
        for (int j = 0; j < 4; j++) {
          u32 pk = (u32)f2bf(va[j]) | ((u32)f2bf(vb[j]) << 16);
          dst[(4*qq + j)*40 + s*20 + slot] = pk;
        }
        pmA[p*2 + s] = fmaxf(fmaxf(va.x, va.y), fmaxf(va.z, va.w));
        pmB[p*2 + s] = fmaxf(fmaxf(vb.x, vb.y), fmaxf(vb.z, vb.w));
      }
    }
    asm volatile("s_waitcnt lgkmcnt(0)" ::: "memory");
    __builtin_amdgcn_s_barrier();
    if (p < 2) {
      #pragma unroll
      for (int s = 0; s < 2; s++)
        #pragma unroll
        for (int h = 0; h < 2; h++)
          xr[p & 1][s][h] = *(const f32x4*)(xsrc + (size_t)(((p+2)*2 + s)*32 + h)*HW);
    }
    #pragma unroll
    for (int s = 0; s < 2; s++) {
      int sl = p*2 + s;
      s16x8 af[4];
      #pragma unroll
      for (int tm = 0; tm < 4; tm++)
        af[tm] = *(const s16x8*)(wpk + ((size_t)(sl*4 + g)*256 + mrow + tm*16)*8);
      const u32* xb = xbuf + (p & 1)*2560 + s*20;
      #pragma unroll
      for (int tn = 0; tn < 4; tn++) {
        int px = 16*tn + ln;
        int gr = g ^ ((px >> 2) & 3);
        s16x8 bfr = *(const s16x8*)((const u16*)&xb[px*40 + gr*4]);
        #pragma unroll
        for (int tm = 0; tm < 4; tm++)
          acc[tm][tn] = __builtin_amdgcn_mfma_f32_16x16x32_bf16(af[tm], bfr, acc[tm][tn], 0, 0, 0);
      }
    }
  }

  // ---- pooling partial reduce (LDS pitch 17, conflict-free; zero atomics) ----
  __syncthreads();
  float* pml = (float*)smem;                     // [256 ch][17]
  #pragma unroll
  for (int sl = 0; sl < 8; sl++) {
    pml[(sl*32 + 2*c2)*17 + qq]     = pmA[sl];
    pml[(sl*32 + 2*c2 + 1)*17 + qq] = pmB[sl];
  }
  __syncthreads();
  {
    float m0 = -3.4e38f, m1 = -3.4e38f, m2 = -3.4e38f, m3 = -3.4e38f;
    #pragma unroll
    for (int q = 0; q < 16; q++) {
      float v = pml[t*17 + q];
      int cl = (cb0 + 4*q)/24 - cblk0;
      m0 = (cl == 0) ? fmaxf(m0, v) : m0;
      m1 = (cl == 1) ? fmaxf(m1, v) : m1;
      m2 = (cl == 2) ? fmaxf(m2, v) : m2;
      m3 = (cl == 3) ? fmaxf(m3, v) : m3;
    }
    float* pmp = wsb + WS_PMP + (((size_t)b*NCH + t)*576 + tile)*4;
    pmp[0] = m0;
    if (1 <= maxcl) pmp[1] = m1;
    if (2 <= maxcl) pmp[2] = m2;
    if (3 <= maxcl) pmp[3] = m3;
  }
  __syncthreads();

  float* s1p = wsb + WS_S1P + (((size_t)b*576 + tile)*256)*8;

  if (YBF) {
    u16* ytile = (u16*)smem;                     // [256 o][72]
    #pragma unroll
    for (int tm = 0; tm < 4; tm++)
      #pragma unroll
      for (int r = 0; r < 4; r++) {
        int orow = w*64 + tm*16 + g*4 + r;
        #pragma unroll
        for (int tn = 0; tn < 4; tn++)
          ytile[orow*72 + 16*tn + ln] = f2bf(acc[tm][tn][r]);
      }
    __syncthreads();
    int seg = t & 7, oo = t >> 3;
    int lbase = l & 56;
    int cl_s = (cb0 + 8*seg)/24 - cblk0;
    int nx1 = (seg < 7) ? ((cb0 + 8*(seg+1))/24 - cblk0) : 99;
    int nx2 = (seg < 6) ? ((cb0 + 8*(seg+2))/24 - cblk0) : 99;
    bool i1 = (nx1 == cl_s), i2 = (nx2 == cl_s);
    bool ist = (seg == 0) || (((cb0 + 8*seg) % 24) == 0);
    u16* ybb = (u16*)(wsb + WS_YBF) + (size_t)b*NCH*HW + n0;
    #pragma unroll
    for (int r8i = 0; r8i < 8; r8i++) {
      int o = r8i*32 + oo;
      u16x8 v = *(const u16x8*)(&ytile[o*72 + seg*8]);
      *(u16x8*)(ybb + (size_t)o*HW + seg*8) = v;
      float sval = 0.f, sq = 0.f;
      #pragma unroll
      for (int e = 0; e < 8; e++) { float yr = bf2f(v[e]); sval += yr; sq += yr*yr; }
      float s2t = sq;
      s2t += __shfl_xor(s2t, 1); s2t += __shfl_xor(s2t, 2); s2t += __shfl_xor(s2t, 4);
      float v1 = __shfl(sval, lbase + ((seg + 1) & 7));
      float v2 = __shfl(sval, lbase + ((seg + 2) & 7));
      float cell = sval + (i1 ? v1 : 0.f) + (i2 ? v2 : 0.f);
      if (ist) s1p[(size_t)o*8 + cl_s] = cell;
      if (seg == 0) s1p[(size_t)o*8 + 4] = s2t;
    }
  } else {
    float* yf = y + (size_t)b*NCH*HW + n0;
    int ci_[4];
    #pragma unroll
    for (int tn = 0; tn < 4; tn++) ci_[tn] = (cb0 + 16*tn + ln)/24 - cblk0;
    #pragma unroll
    for (int tm = 0; tm < 4; tm++)
      #pragma unroll
      for (int r = 0; r < 4; r++) {
        int o = w*64 + tm*16 + g*4 + r;
        float sv0 = 0.f, sv1 = 0.f, sv2 = 0.f, sv3 = 0.f, s2 = 0.f;
        #pragma unroll
        for (int tn = 0; tn < 4; tn++) {
          int px = 16*tn + ln;
          float v = acc[tm][tn][r];
          yf[(size_t)o*HW + px] = v;
          s2 += v*v;
          sv0 += (ci_[tn] == 0) ? v : 0.f;
          sv1 += (ci_[tn] == 1) ? v : 0.f;
          sv2 += (ci_[tn] == 2) ? v : 0.f;
          sv3 += (ci_[tn] == 3) ? v : 0.f;
        }
        #pragma unroll
        for (int off = 1; off < 16; off <<= 1) {
          sv0 += __shfl_xor(sv0, off); sv1 += __shfl_xor(sv1, off);
          sv2 += __shfl_xor(sv2, off); sv3 += __shfl_xor(sv3, off);
          s2  += __shfl_xor(s2, off);
        }
        if (ln < 4) {
          float out = (ln == 0) ? sv0 : (ln == 1) ? sv1 : (ln == 2) ? sv2 : sv3;
          s1p[(size_t)o*8 + ln] = out;
        }
        if (ln == 0) s1p[(size_t)o*8 + 4] = s2;
      }
  }
}

// K2: PMP partials -> 85-entry pyramids per (b,c)
__global__ __launch_bounds__(64) void k_pred(float* __restrict__ wsb) {
  __shared__ float sm3[64], sm2[16], sm1[4];
  int bc = blockIdx.x;
  int t = threadIdx.x;                       // cell
  int by = t >> 3, bx = t & 7;
  const float* pmp = wsb + WS_PMP + (size_t)bc*576*4;
  int tc0 = (24*bx)/64, tc1 = (24*bx + 23)/64;
  float m = -3.4e38f;
  for (int r = 0; r < 24; r++) {
    int row = by*24 + r;
    for (int tc = tc0; tc <= tc1; tc++) {
      int cblk0 = (tc*64)/24;
      m = fmaxf(m, pmp[(size_t)(row*3 + tc)*4 + (bx - cblk0)]);
    }
  }
  sm3[t] = m;
  __syncthreads();
  float* pb = wsb + WS_PALL + (size_t)bc*POS;
  pb[t] = m;
  if (t < 16) {
    int i = t >> 2, j = t & 3;
    float mm = fmaxf(fmaxf(sm3[(2*i)*8 + 2*j], sm3[(2*i)*8 + 2*j + 1]),
                     fmaxf(sm3[(2*i+1)*8 + 2*j], sm3[(2*i+1)*8 + 2*j + 1]));
    sm2[t] = mm; pb[64 + t] = mm;
  }
  __syncthreads();
  if (t < 4) {
    int i = t >> 1, j = t & 1;
    float mm = fmaxf(fmaxf(sm2[(2*i)*4 + 2*j], sm2[(2*i)*4 + 2*j + 1]),
                     fmaxf(sm2[(2*i+1)*4 + 2*j], sm2[(2*i+1)*4 + 2*j + 1]));
    sm1[t] = mm; pb[80 + t] = mm;
  }
  __syncthreads();
  if (t == 0)
    pb[84] = fmaxf(fmaxf(sm1[0], sm1[1]), fmaxf(sm1[2], sm1[3]));
}

// K3: pyramid convs on distinct block values + BN stat accumulation (unchanged)
__global__ __launch_bounds__(256) void k_pyr(const float* __restrict__ wconv, float* __restrict__ wsb) {
  __shared__ __align__(16) float pv[256];
  int bi = blockIdx.x;                       // b*85 + pos
  int b = bi / 85, pos = bi % 85;
  int d = (pos < 64) ? 3 : (pos < 80) ? 2 : (pos < 84) ? 1 : 0;
  int t = threadIdx.x;
  pv[t] = wsb[WS_PALL + (size_t)(b*NCH + t)*POS + pos];
  __syncthreads();
  const float* wrow = wconv + ((size_t)d*NCH + t)*NCH;
  float acc = 0.f;
  #pragma unroll 4
  for (int c4 = 0; c4 < 64; c4++) {
    f32x4 wv = *(const f32x4*)(wrow + c4*4);
    f32x4 xv = *(const f32x4*)(&pv[c4*4]);
    acc += wv.x*xv.x + wv.y*xv.y + wv.z*xv.z + wv.w*xv.w;
  }
  wsb[WS_YD + (size_t)(b*NCH + t)*POS + pos] = acc;
  atomicAdd(&wsb[WS_PSUM + d*NCH + t], acc);
  atomicAdd(&wsb[WS_PSQ  + d*NCH + t], acc*acc);
}

// K4: contrib[b][o][cell] += per-depth partial (r11-proven, grid = d*64 + cell)
__global__ __launch_bounds__(256) void k_contrib(const float* __restrict__ wf,
                                                 const float* __restrict__ gs,
                                                 const float* __restrict__ bs,
                                                 float* __restrict__ wsb) {
  __shared__ __align__(16) float pn[4][256];
  int bi = blockIdx.x;
  int d = bi >> 6, cell = bi & 63;
  int by = cell >> 3, bx = cell & 7;
  int t = threadIdx.x;
  int pos = (d == 3) ? cell
          : (d == 2) ? 64 + (by >> 1)*4 + (bx >> 1)
          : (d == 1) ? 80 + (by >> 2)*2 + (bx >> 2)
          : 84;
  float cnt = (float)(4 << (2*d));
  float mu  = wsb[WS_PSUM + d*NCH + t] / cnt;
  float var = wsb[WS_PSQ  + d*NCH + t] / cnt - mu*mu;
  float sc  = gs[d*NCH + t] * rsqrtf(var + BN_EPS);
  float bi_ = bs[d*NCH + t] - mu * sc;
  #pragma unroll
  for (int b = 0; b < 4; b++)
    pn[b][t] = wsb[WS_YD + (size_t)(b*NCH + t)*POS + pos] * sc + bi_;
  __syncthreads();
  const float* wrow = wf + (size_t)t*1280 + 256 + d*256;
  float a0 = 0.f, a1 = 0.f, a2 = 0.f, a3 = 0.f;
  #pragma unroll 4
  for (int j = 0; j < 64; j++) {
    f32x4 wv = *(const f32x4*)(wrow + j*4);
    f32x4 p0 = *(const f32x4*)(&pn[0][j*4]);
    f32x4 p1 = *(const f32x4*)(&pn[1][j*4]);
    f32x4 p2 = *(const f32x4*)(&pn[2][j*4]);
    f32x4 p3 = *(const f32x4*)(&pn[3][j*4]);
    a0 += wv.x*p0.x + wv.y*p0.y + wv.z*p0.z + wv.w*p0.w;
    a1 += wv.x*p1.x + wv.y*p1.y + wv.z*p1.z + wv.w*p1.w;
    a2 += wv.x*p2.x + wv.y*p2.y + wv.z*p2.z + wv.w*p2.w;
    a3 += wv.x*p3.x + wv.y*p3.y + wv.z*p3.z + wv.w*p3.w;
  }
  atomicAdd(&wsb[WS_CONTRIB + (size_t)(0*NCH + t)*64 + cell], a0);
  atomicAdd(&wsb[WS_CONTRIB + (size_t)(1*NCH + t)*64 + cell], a1);
  atomicAdd(&wsb[WS_CONTRIB + (size_t)(2*NCH + t)*64 + cell], a2);
  atomicAdd(&wsb[WS_CONTRIB + (size_t)(3*NCH + t)*64 + cell], a3);
}

// K5: final BN stats via decomposition (r8 formula); emit sc[o], add[b][o][cell]
__global__ __launch_bounds__(256) void k_fstats(const float* __restrict__ gf,
                                                const float* __restrict__ bfv,
                                                float* __restrict__ wsb) {
  __shared__ float cs1[4][64];
  __shared__ float red[12];
  int o = blockIdx.x, t = threadIdx.x;
  cs1[t >> 6][t & 63] = 0.f;
  __syncthreads();
  float sq = 0.f;
  for (int e = t; e < 9216; e += 256) {          // (b, tile, slot)
    int slotv = e & 3, bt = e >> 2;
    int tile = bt % 576, b = bt / 576;
    int tm3 = tile % 3;
    int mcl = (tm3 == 1) ? 3 : 2;
    if (slotv <= mcl) {
      float v = wsb[WS_S1P + (((size_t)b*576 + tile)*256 + o)*8 + slotv];
      int cblk0 = (tm3 == 0) ? 0 : (tm3 == 1) ? 2 : 5;
      int cell = ((tile/3)/24)*8 + cblk0 + slotv;
      atomicAdd(&cs1[b][cell], v);
    }
  }
  for (int e = t; e < 2304; e += 256) {          // sumsq partials
    int tile = e % 576, b = e / 576;
    sq += wsb[WS_S1P + (((size_t)b*576 + tile)*256 + o)*8 + 4];
  }
  __syncthreads();
  int b4 = t >> 6, cell4 = t & 63;
  float C  = wsb[WS_CONTRIB + ((size_t)(b4*NCH + o))*64 + cell4];
  float s1 = cs1[b4][cell4];
  float p1 = s1 + 576.f*C;
  float p2 = C*(2.f*s1 + 576.f*C);
  #pragma unroll
  for (int off = 1; off < 64; off <<= 1) {
    p1 += __shfl_xor(p1, off);
    p2 += __shfl_xor(p2, off);
    sq += __shfl_xor(sq, off);
  }
  int wv = t >> 6;
  if ((t & 63) == 0) { red[wv] = p1; red[4 + wv] = p2; red[8 + wv] = sq; }
  __syncthreads();
  if (t == 0) {
    float sum1 = red[0] + red[1] + red[2] + red[3];
    float sum2 = red[4] + red[5] + red[6] + red[7]
               + red[8] + red[9] + red[10] + red[11];
    float inv = 1.f / (float)NPIX;
    float mu  = sum1 * inv;
    float var = sum2 * inv - mu*mu;
    float sc  = gf[o] * rsqrtf(var + BN_EPS);
    float bi  = bfv[o] - mu * sc;
    wsb[WS_SC + o] = sc;
    red[0] = sc; red[1] = bi;
  }
  __syncthreads();
  float sc = red[0], bi = red[1];
  wsb[WS_ADD + ((size_t)(b4*NCH + o))*64 + cell4] = bi + C*sc;
}

// K6: normalize: out = G*sc + add[b][o][cell]  (r8-proven shape)
template<bool YBF>
__global__ __launch_bounds__(256) void k_norm(float* __restrict__ out,
                                              const float* __restrict__ wsb) {
  __shared__ float a16[16];
  int bid = blockIdx.x;                      // plane*4 + quarter
  int plane = bid >> 2, q = bid & 3;         // plane = b*256 + o
  int t = threadIdx.x;
  float sc = wsb[WS_SC + (plane & 255)];
  if (t < 16)
    a16[t] = wsb[WS_ADD + (size_t)plane*64 + (2*q + (t >> 3))*8 + (t & 7)];
  __syncthreads();
  size_t base4 = ((size_t)plane*HW + q*(HW/4)) >> 2;
  if (YBF) {
    const u16* yb = (const u16*)(wsb + WS_YBF);
    #pragma unroll
    for (int it = 0; it < 9; it++) {
      int pl = 4*(it*256 + t);
      int rl = pl / 192;
      int cc = (pl - rl*192) / 24;
      float ad = a16[(rl/24)*8 + cc];
      size_t i4 = base4 + it*256 + t;
      u16x4 v = *(const u16x4*)(yb + i4*4);
      f32x4 o;
      o.x = bf2f(v[0])*sc + ad;
      o.y = bf2f(v[1])*sc + ad;
      o.z = bf2f(v[2])*sc + ad;
      o.w = bf2f(v[3])*sc + ad;
      ((f32x4*)out)[i4] = o;
    }
  } else {
    #pragma unroll
    for (int it = 0; it < 9; it++) {
      int pl = 4*(it*256 + t);
      int rl = pl / 192;
      int cc = (pl - rl*192) / 24;
      float ad = a16[(rl/24)*8 + cc];
      size_t i4 = base4 + it*256 + t;
      f32x4 v = ((f32x4*)out)[i4];
      v.x = v.x*sc + ad; v.y = v.y*sc + ad; v.z = v.z*sc + ad; v.w = v.w*sc + ad;
      ((f32x4*)out)[i4] = v;
    }
  }
}

extern "C" void kernel_launch(void* const* d_in, const int* in_sizes, int n_in,
                              void* d_out, int out_size, void* d_ws, size_t ws_size,
                              hipStream_t stream) {
  const float* x  = (const float*)d_in[0];
  const float* w  = (const float*)d_in[1];
  const float* gs = (const float*)d_in[2];
  const float* bs = (const float*)d_in[3];
  const float* wf = (const float*)d_in[4];
  const float* gf = (const float*)d_in[5];
  const float* bf = (const float*)d_in[6];
  float* y   = (float*)d_out;
  float* wsb = (float*)d_ws;

  bool ybf = ws_size >= (size_t)WS_TOT1 * sizeof(float);

  k_prep   <<<296, 256, 0, stream>>>(wf, wsb);
  if (ybf) k_main<true> <<<NB*576, 256, 0, stream>>>(x, wsb, y);
  else     k_main<false><<<NB*576, 256, 0, stream>>>(x, wsb, y);
  k_pred   <<<NB*NCH, 64, 0, stream>>>(wsb);
  k_pyr    <<<NB*POS, 256, 0, stream>>>(w, wsb);
  k_contrib<<<256, 256, 0, stream>>>(wf, gs, bs, wsb);
  k_fstats <<<256, 256, 0, stream>>>(gf, bf, wsb);
  if (ybf) k_norm<true> <<<4096, 256, 0, stream>>>(y, wsb);
  else     k_norm<false><<<4096, 256, 0, stream>>>(y, wsb);
}

// Round 13
// 181.496 us; speedup vs baseline: 1.1428x; 1.1428x over previous
//
#include <hip/hip_runtime.h>

typedef unsigned short u16;
typedef unsigned int   u32;
typedef __attribute__((ext_vector_type(4))) float f32x4;
typedef __attribute__((ext_vector_type(8))) short s16x8;
typedef __attribute__((ext_vector_type(4))) unsigned short u16x4;
typedef __attribute__((ext_vector_type(8))) unsigned short u16x8;

#define HW    36864
#define NCH   256
#define NB    4
#define NPIX  147456
#define POS   85
#define BN_EPS 1e-5f
#define NBKT  16

// ---- workspace float offsets ----
#define WS_PALL    0            // 4*256*85 = 87040
#define WS_YD      87040        // 87040
#define WS_PSUM    174080       // 1024
#define WS_PSQ     175104       // 1024
#define WS_CONTRIB 176128       // 65536 (atomic accumulated; zeroed by k_pool blk 0)
#define WS_FSUMB   241664       // 4096
#define WS_FSQB    245760       // 4096
#define WS_WPK     249856       // u16[65536] = 32768 floats
#define WS_YBF     282624       // u16 y: 18874368 floats
#define WS_TOT1    (WS_YBF + NB*NCH*HW/2)

__device__ __forceinline__ u16 f2bf(float f) {
  u32 u = __builtin_bit_cast(u32, f);
  u += 0x7fffu + ((u >> 16) & 1u);
  return (u16)(u >> 16);
}
__device__ __forceinline__ float bf2f(u16 h) {
  u32 u = ((u32)h) << 16;
  return __builtin_bit_cast(float, u);
}

// K1: blocks 0..1023: per-(b,c) plane -> 85-entry block-max pyramid (r2-proven).
//     blocks 1024..1067: pack wf[:, :256] -> bf16 A-frags (folded k_wpack).
__global__ __launch_bounds__(192) void k_pool(const float* __restrict__ x,
                                              const float* __restrict__ wf,
                                              float* __restrict__ wsb) {
  int blk = blockIdx.x;
  int t = threadIdx.x;
  if (blk >= 1024) {
    int fid = (blk - 1024)*192 + t;          // [ks32][g][m]
    if (fid < 8192) {
      int m = fid & 255, g = (fid >> 8) & 3, ks = fid >> 10;
      const float* src = wf + (size_t)m*1280 + ks*32 + g*8;
      f32x4 a = *(const f32x4*)src;
      f32x4 c = *(const f32x4*)(src + 4);
      u32* dst = (u32*)((u16*)(wsb + WS_WPK) + (size_t)fid*8);
      dst[0] = (u32)f2bf(a.x) | ((u32)f2bf(a.y) << 16);
      dst[1] = (u32)f2bf(a.z) | ((u32)f2bf(a.w) << 16);
      dst[2] = (u32)f2bf(c.x) | ((u32)f2bf(c.y) << 16);
      dst[3] = (u32)f2bf(c.z) | ((u32)f2bf(c.w) << 16);
    }
    return;
  }
  __shared__ float sm[8][4][48];
  __shared__ float sp[84];
  int bc = blk;                              // b*256 + c
  const float* base = x + (size_t)bc * HW;
  int cg = t % 48, rg = t / 48;
  if (bc == 0) {                             // zero stat + contrib accumulators
    for (int i = t; i < 2048; i += 192) wsb[WS_PSUM + i] = 0.f;
    for (int i = t; i < 8192; i += 192) wsb[WS_FSUMB + i] = 0.f;
    for (int i = t; i < 65536; i += 192) wsb[WS_CONTRIB + i] = 0.f;
  }
  #pragma unroll
  for (int byi = 0; byi < 8; byi++) {
    float mm = -3.4e38f;
    #pragma unroll
    for (int rr = 0; rr < 6; rr++) {
      int r = byi*24 + rg + 4*rr;
      f32x4 v = *(const f32x4*)(base + r*192 + cg*4);
      mm = fmaxf(mm, fmaxf(fmaxf(v.x, v.y), fmaxf(v.z, v.w)));
    }
    sm[byi][rg][cg] = mm;
  }
  __syncthreads();
  size_t pb = WS_PALL + (size_t)bc * POS;
  if (t < 64) {
    int by = t >> 3, bx = t & 7;
    float mm = -3.4e38f;
    for (int r2 = 0; r2 < 4; r2++)
      for (int cq = 0; cq < 6; cq++)
        mm = fmaxf(mm, sm[by][r2][bx*6 + cq]);
    sp[t] = mm;
    wsb[pb + t] = mm;
  }
  __syncthreads();
  if (t < 16) {
    int i = t >> 2, j = t & 3;
    float mm = fmaxf(fmaxf(sp[(2*i)*8 + 2*j], sp[(2*i)*8 + 2*j + 1]),
                     fmaxf(sp[(2*i+1)*8 + 2*j], sp[(2*i+1)*8 + 2*j + 1]));
    sp[64 + t] = mm;
    wsb[pb + 64 + t] = mm;
  }
  __syncthreads();
  if (t < 4) {
    int i = t >> 1, j = t & 1;
    float mm = fmaxf(fmaxf(sp[64 + (2*i)*4 + 2*j], sp[64 + (2*i)*4 + 2*j + 1]),
                     fmaxf(sp[64 + (2*i+1)*4 + 2*j], sp[64 + (2*i+1)*4 + 2*j + 1]));
    sp[80 + t] = mm;
    wsb[pb + 80 + t] = mm;
  }
  __syncthreads();
  if (t == 0)
    wsb[pb + 84] = fmaxf(fmaxf(sp[80], sp[81]), fmaxf(sp[82], sp[83]));
}

// K2: pyramid convs on distinct block values + BN stat accumulation
__global__ __launch_bounds__(256) void k_pyr(const float* __restrict__ wconv, float* __restrict__ wsb) {
  __shared__ __align__(16) float pv[256];
  int bi = blockIdx.x;                       // b*85 + pos
  int b = bi / 85, pos = bi % 85;
  int d = (pos < 64) ? 3 : (pos < 80) ? 2 : (pos < 84) ? 1 : 0;
  int t = threadIdx.x;
  pv[t] = wsb[WS_PALL + (size_t)(b*NCH + t)*POS + pos];
  __syncthreads();
  const float* wrow = wconv + ((size_t)d*NCH + t)*NCH;
  float acc = 0.f;
  #pragma unroll 4
  for (int c4 = 0; c4 < 64; c4++) {
    f32x4 wv = *(const f32x4*)(wrow + c4*4);
    f32x4 xv = *(const f32x4*)(&pv[c4*4]);
    acc += wv.x*xv.x + wv.y*xv.y + wv.z*xv.z + wv.w*xv.w;
  }
  wsb[WS_YD + (size_t)(b*NCH + t)*POS + pos] = acc;
  atomicAdd(&wsb[WS_PSUM + d*NCH + t], acc);
  atomicAdd(&wsb[WS_PSQ  + d*NCH + t], acc*acc);
}

// K3: contrib[b][o][cell] += per-depth partial (grid = d*64 + cell; r11-proven)
__global__ __launch_bounds__(256) void k_contrib(const float* __restrict__ wf,
                                                 const float* __restrict__ gs,
                                                 const float* __restrict__ bs,
                                                 float* __restrict__ wsb) {
  __shared__ __align__(16) float pn[4][256];    // [b][c]
  int bi = blockIdx.x;
  int d = bi >> 6, cell = bi & 63;
  int by = cell >> 3, bx = cell & 7;
  int t = threadIdx.x;
  int pos = (d == 3) ? cell
          : (d == 2) ? 64 + (by >> 1)*4 + (bx >> 1)
          : (d == 1) ? 80 + (by >> 2)*2 + (bx >> 2)
          : 84;
  float cnt = (float)(4 << (2*d));
  float mu  = wsb[WS_PSUM + d*NCH + t] / cnt;
  float var = wsb[WS_PSQ  + d*NCH + t] / cnt - mu*mu;
  float sc  = gs[d*NCH + t] * rsqrtf(var + BN_EPS);
  float bi_ = bs[d*NCH + t] - mu * sc;
  #pragma unroll
  for (int b = 0; b < 4; b++)
    pn[b][t] = wsb[WS_YD + (size_t)(b*NCH + t)*POS + pos] * sc + bi_;
  __syncthreads();
  const float* wrow = wf + (size_t)t*1280 + 256 + d*256;
  float a0 = 0.f, a1 = 0.f, a2 = 0.f, a3 = 0.f;
  #pragma unroll 4
  for (int j = 0; j < 64; j++) {
    f32x4 wv = *(const f32x4*)(wrow + j*4);
    f32x4 p0 = *(const f32x4*)(&pn[0][j*4]);
    f32x4 p1 = *(const f32x4*)(&pn[1][j*4]);
    f32x4 p2 = *(const f32x4*)(&pn[2][j*4]);
    f32x4 p3 = *(const f32x4*)(&pn[3][j*4]);
    a0 += wv.x*p0.x + wv.y*p0.y + wv.z*p0.z + wv.w*p0.w;
    a1 += wv.x*p1.x + wv.y*p1.y + wv.z*p1.z + wv.w*p1.w;
    a2 += wv.x*p2.x + wv.y*p2.y + wv.z*p2.z + wv.w*p2.w;
    a3 += wv.x*p3.x + wv.y*p3.y + wv.z*p3.z + wv.w*p3.w;
  }
  atomicAdd(&wsb[WS_CONTRIB + (size_t)(0*NCH + t)*64 + cell], a0);
  atomicAdd(&wsb[WS_CONTRIB + (size_t)(1*NCH + t)*64 + cell], a1);
  atomicAdd(&wsb[WS_CONTRIB + (size_t)(2*NCH + t)*64 + cell], a2);
  atomicAdd(&wsb[WS_CONTRIB + (size_t)(3*NCH + t)*64 + cell], a3);
}

// K4: main GEMM (r11 structure) + full-depth x prefetch (all 16 loads in
//     prologue) + W-frag double-buffer. Epilogue identical to r11.
template<bool YBF>
__global__ __launch_bounds__(256, 3) void k_main(const float* __restrict__ x,
                                                 float* __restrict__ wsb, float* __restrict__ y) {
  __shared__ __align__(16) char smem[40960];     // union: xbuf 2x10240B | ytile 36864B
  __shared__ float ctile[256*4];                 // 4 KB
  u32* xbuf = (u32*)smem;                        // [buf][px*40 u32]
  int wg = blockIdx.x;
  int b = wg / 576, tile = wg % 576;
  int n0 = tile * 64;
  int t = threadIdx.x, w = t >> 6, l = t & 63, g = l >> 4, ln = l & 15;
  int cb0 = (tile % 3) * 64;
  int rowblk = (tile / 3) / 24;
  int cblk0 = cb0 / 24;
  const u16* wpk = (const u16*)(wsb + WS_WPK);
  int mrow = w*64 + ln;
  int qq = t & 15, c2 = t >> 4;                  // staging: px-quad, channel-pair
  const float* xsrc = x + (size_t)(b*NCH + 2*c2)*HW + n0 + 4*qq;

  // ctile global loads (issued first)
  float ct[4];
  {
    const float* cbase = wsb + WS_CONTRIB + ((size_t)b*NCH + t)*64 + rowblk*8;
    #pragma unroll
    for (int i = 0; i < 4; i++) {
      int cc = cblk0 + i; if (cc > 7) cc = 7;
      ct[i] = cbase[cc];
    }
  }
  // prologue: ALL x loads for phases 0..3 (16 f32x4, 256 B/thread in flight)
  f32x4 xr[4][2][2];                             // [phase][slab-in-phase][ch]
  #pragma unroll
  for (int pp = 0; pp < 4; pp++)
    #pragma unroll
    for (int s = 0; s < 2; s++)
      #pragma unroll
      for (int h = 0; h < 2; h++)
        xr[pp][s][h] = *(const f32x4*)(xsrc + (size_t)((pp*2 + s)*32 + h)*HW);

  // W-frag double buffer; prefetch slab 0
  s16x8 af[2][4];
  #pragma unroll
  for (int tm = 0; tm < 4; tm++)
    af[0][tm] = *(const s16x8*)(wpk + ((size_t)g*256 + mrow + tm*16)*8);

  #pragma unroll
  for (int i = 0; i < 4; i++) ctile[t*4 + i] = ct[i];
  asm volatile("s_waitcnt lgkmcnt(0)" ::: "memory");
  __builtin_amdgcn_s_barrier();

  f32x4 acc[4][4];
  #pragma unroll
  for (int i = 0; i < 4; i++)
    #pragma unroll
    for (int j = 0; j < 4; j++)
      acc[i][j] = {0.f, 0.f, 0.f, 0.f};

  int slot = (((c2 >> 2) ^ (qq & 3)) << 2) | (c2 & 3);   // group-XOR swizzle

  #pragma unroll
  for (int p = 0; p < 4; p++) {
    // stage phase p (slabs 2p, 2p+1) into buf[p&1]
    {
      u32* dst = xbuf + (p & 1)*2560;
      #pragma unroll
      for (int s = 0; s < 2; s++) {
        f32x4 va = xr[p][s][0], vb = xr[p][s][1];
        #pragma unroll
        for (int j = 0; j < 4; j++) {
          u32 pk = (u32)f2bf(va[j]) | ((u32)f2bf(vb[j]) << 16);
          dst[(4*qq + j)*40 + s*20 + slot] = pk;
        }
      }
    }
    asm volatile("s_waitcnt lgkmcnt(0)" ::: "memory");
    __builtin_amdgcn_s_barrier();
    // compute both slabs of phase p; prefetch next slab's W-frags over MFMAs
    #pragma unroll
    for (int s = 0; s < 2; s++) {
      int sl = p*2 + s;
      if (sl < 7) {
        #pragma unroll
        for (int tm = 0; tm < 4; tm++)
          af[(sl+1) & 1][tm] = *(const s16x8*)(wpk + ((size_t)((sl+1)*4 + g)*256 + mrow + tm*16)*8);
      }
      const u32* xb = xbuf + (p & 1)*2560 + s*20;
      #pragma unroll
      for (int tn = 0; tn < 4; tn++) {
        int px = 16*tn + ln;
        int gr = g ^ ((px >> 2) & 3);
        s16x8 bfr = *(const s16x8*)((const u16*)&xb[px*40 + gr*4]);
        #pragma unroll
        for (int tm = 0; tm < 4; tm++)
          acc[tm][tn] = __builtin_amdgcn_mfma_f32_16x16x32_bf16(af[sl & 1][tm], bfr, acc[tm][tn], 0, 0, 0);
      }
    }
  }

  // epilogue: add contrib, stats, bf16 into ytile (union: wait for all LDS readers)
  __syncthreads();
  u16* ytile = (u16*)smem;                       // [256 o][72 px pitch]
  int ci[4];
  #pragma unroll
  for (int tn = 0; tn < 4; tn++)
    ci[tn] = (cb0 + 16*tn + ln)/24 - cblk0;
  int bkt = wg & (NBKT - 1);
  float* fsum = wsb + WS_FSUMB + bkt*256;
  float* fsq  = wsb + WS_FSQB  + bkt*256;
  float* yf   = y + (size_t)b*NCH*HW + n0;
  #pragma unroll
  for (int tm = 0; tm < 4; tm++) {
    #pragma unroll
    for (int r = 0; r < 4; r++) {
      int o = w*64 + tm*16 + g*4 + r;
      float s1 = 0.f, s2 = 0.f;
      #pragma unroll
      for (int tn = 0; tn < 4; tn++) {
        int px = 16*tn + ln;
        float v = acc[tm][tn][r] + ctile[o*4 + ci[tn]];
        if (YBF) {
          u16 h = f2bf(v);
          ytile[o*72 + px] = h;
          float yr = bf2f(h);
          s1 += yr; s2 += yr*yr;
        } else {
          yf[(size_t)o*HW + px] = v;
          s1 += v; s2 += v*v;
        }
      }
      s1 += __shfl_xor(s1, 1);  s2 += __shfl_xor(s2, 1);
      s1 += __shfl_xor(s1, 2);  s2 += __shfl_xor(s2, 2);
      s1 += __shfl_xor(s1, 4);  s2 += __shfl_xor(s2, 4);
      s1 += __shfl_xor(s1, 8);  s2 += __shfl_xor(s2, 8);
      if (ln == 0) { atomicAdd(&fsum[o], s1); atomicAdd(&fsq[o], s2); }
    }
  }
  if (YBF) {
    __syncthreads();
    // coalesced store: 8 rounds; lane = (o' = t>>3 within 32-o group, seg = t&7)
    u16* ybb = (u16*)(wsb + WS_YBF) + (size_t)b*NCH*HW + n0;
    int oo = t >> 3, seg = t & 7;
    #pragma unroll
    for (int r8 = 0; r8 < 8; r8++) {
      int o = r8*32 + oo;
      u16x8 v = *(const u16x8*)(&ytile[o*72 + seg*8]);
      *(u16x8*)(ybb + (size_t)o*HW + seg*8) = v;
    }
  }
}

// K5: normalize with inline final BN stats (r2-proven coalesced shape)
template<bool YBF>
__global__ __launch_bounds__(256) void k_norm(float* __restrict__ out,
                                              const float* __restrict__ gf,
                                              const float* __restrict__ bfv,
                                              const float* __restrict__ wsb) {
  int bid = blockIdx.x;                      // plane*4 + quarter
  int plane = bid >> 2, q = bid & 3;
  int c = plane & 255;
  float s1 = 0.f, s2 = 0.f;
  #pragma unroll
  for (int i = 0; i < NBKT; i++) {
    s1 += wsb[WS_FSUMB + i*256 + c];
    s2 += wsb[WS_FSQB  + i*256 + c];
  }
  float inv = 1.f / (float)NPIX;
  float mu  = s1 * inv;
  float var = s2 * inv - mu*mu;
  float sc  = gf[c] * rsqrtf(var + BN_EPS);
  float bi  = bfv[c] - mu * sc;
  size_t base4 = ((size_t)plane*HW + q*(HW/4)) >> 2;   // f32x4 / u16x4 index
  int t = threadIdx.x;
  if (YBF) {
    const u16* yb = (const u16*)(wsb + WS_YBF);
    #pragma unroll
    for (int it = 0; it < 9; it++) {
      size_t i4 = base4 + it*256 + t;
      u16x4 v = *(const u16x4*)(yb + i4*4);
      f32x4 o;
      o.x = bf2f(v[0])*sc + bi;
      o.y = bf2f(v[1])*sc + bi;
      o.z = bf2f(v[2])*sc + bi;
      o.w = bf2f(v[3])*sc + bi;
      ((f32x4*)out)[i4] = o;
    }
  } else {
    #pragma unroll
    for (int it = 0; it < 9; it++) {
      size_t i4 = base4 + it*256 + t;
      f32x4 v = ((f32x4*)out)[i4];
      v.x = v.x*sc + bi; v.y = v.y*sc + bi; v.z = v.z*sc + bi; v.w = v.w*sc + bi;
      ((f32x4*)out)[i4] = v;
    }
  }
}

extern "C" void kernel_launch(void* const* d_in, const int* in_sizes, int n_in,
                              void* d_out, int out_size, void* d_ws, size_t ws_size,
                              hipStream_t stream) {
  const float* x  = (const float*)d_in[0];
  const float* w  = (const float*)d_in[1];
  const float* gs = (const float*)d_in[2];
  const float* bs = (const float*)d_in[3];
  const float* wf = (const float*)d_in[4];
  const float* gf = (const float*)d_in[5];
  const float* bf = (const float*)d_in[6];
  float* y   = (float*)d_out;
  float* wsb = (float*)d_ws;

  bool ybf = ws_size >= (size_t)WS_TOT1 * sizeof(float);

  k_pool   <<<1068, 192, 0, stream>>>(x, wf, wsb);
  k_pyr    <<<NB*POS, 256, 0, stream>>>(w, wsb);
  k_contrib<<<256, 256, 0, stream>>>(wf, gs, bs, wsb);
  if (ybf) k_main<true> <<<NB*576, 256, 0, stream>>>(x, wsb, y);
  else     k_main<false><<<NB*576, 256, 0, stream>>>(x, wsb, y);
  if (ybf) k_norm<true> <<<4096, 256, 0, stream>>>(y, gf, bf, wsb);
  else     k_norm<false><<<4096, 256, 0, stream>>>(y, gf, bf, wsb);
}

// Round 14
// 176.263 us; speedup vs baseline: 1.1768x; 1.0297x over previous
//
#include <hip/hip_runtime.h>

typedef unsigned short u16;
typedef unsigned int   u32;
typedef __attribute__((ext_vector_type(4))) float f32x4;
typedef __attribute__((ext_vector_type(8))) short s16x8;
typedef __attribute__((ext_vector_type(4))) unsigned short u16x4;
typedef __attribute__((ext_vector_type(8))) unsigned short u16x8;

#define HW    36864
#define NCH   256
#define NB    4
#define NPIX  147456
#define POS   85
#define BN_EPS 1e-5f
#define NBKT  16

// ---- workspace float offsets ----
#define WS_PALL    0            // 4*256*85 = 87040
#define WS_YD      87040        // 87040
#define WS_PSUM    174080       // 1024
#define WS_PSQ     175104       // 1024
#define WS_CONTRIB 176128       // 65536 (atomic accumulated; zeroed by k_pool blk 0)
#define WS_FSUMB   241664       // 4096
#define WS_FSQB    245760       // 4096
#define WS_WPK     249856       // u16[65536] = 32768 floats
#define WS_YBF     282624       // u16 y: 18874368 floats
#define WS_TOT1    (WS_YBF + NB*NCH*HW/2)

__device__ __forceinline__ u16 f2bf(float f) {
  u32 u = __builtin_bit_cast(u32, f);
  u += 0x7fffu + ((u >> 16) & 1u);
  return (u16)(u >> 16);
}
__device__ __forceinline__ float bf2f(u16 h) {
  u32 u = ((u32)h) << 16;
  return __builtin_bit_cast(float, u);
}

// K1: blocks 0..1023: per-(b,c) plane -> 85-entry block-max pyramid (r2-proven).
//     blocks 1024..1067: pack wf[:, :256] -> bf16 A-frags (folded k_wpack).
__global__ __launch_bounds__(192) void k_pool(const float* __restrict__ x,
                                              const float* __restrict__ wf,
                                              float* __restrict__ wsb) {
  int blk = blockIdx.x;
  int t = threadIdx.x;
  if (blk >= 1024) {
    int fid = (blk - 1024)*192 + t;          // [ks32][g][m]
    if (fid < 8192) {
      int m = fid & 255, g = (fid >> 8) & 3, ks = fid >> 10;
      const float* src = wf + (size_t)m*1280 + ks*32 + g*8;
      f32x4 a = *(const f32x4*)src;
      f32x4 c = *(const f32x4*)(src + 4);
      u32* dst = (u32*)((u16*)(wsb + WS_WPK) + (size_t)fid*8);
      dst[0] = (u32)f2bf(a.x) | ((u32)f2bf(a.y) << 16);
      dst[1] = (u32)f2bf(a.z) | ((u32)f2bf(a.w) << 16);
      dst[2] = (u32)f2bf(c.x) | ((u32)f2bf(c.y) << 16);
      dst[3] = (u32)f2bf(c.z) | ((u32)f2bf(c.w) << 16);
    }
    return;
  }
  __shared__ float sm[8][4][48];
  __shared__ float sp[84];
  int bc = blk;                              // b*256 + c
  const float* base = x + (size_t)bc * HW;
  int cg = t % 48, rg = t / 48;
  if (bc == 0) {                             // zero stat + contrib accumulators
    for (int i = t; i < 2048; i += 192) wsb[WS_PSUM + i] = 0.f;
    for (int i = t; i < 8192; i += 192) wsb[WS_FSUMB + i] = 0.f;
    for (int i = t; i < 65536; i += 192) wsb[WS_CONTRIB + i] = 0.f;
  }
  #pragma unroll
  for (int byi = 0; byi < 8; byi++) {
    float mm = -3.4e38f;
    #pragma unroll
    for (int rr = 0; rr < 6; rr++) {
      int r = byi*24 + rg + 4*rr;
      f32x4 v = *(const f32x4*)(base + r*192 + cg*4);
      mm = fmaxf(mm, fmaxf(fmaxf(v.x, v.y), fmaxf(v.z, v.w)));
    }
    sm[byi][rg][cg] = mm;
  }
  __syncthreads();
  size_t pb = WS_PALL + (size_t)bc * POS;
  if (t < 64) {
    int by = t >> 3, bx = t & 7;
    float mm = -3.4e38f;
    for (int r2 = 0; r2 < 4; r2++)
      for (int cq = 0; cq < 6; cq++)
        mm = fmaxf(mm, sm[by][r2][bx*6 + cq]);
    sp[t] = mm;
    wsb[pb + t] = mm;
  }
  __syncthreads();
  if (t < 16) {
    int i = t >> 2, j = t & 3;
    float mm = fmaxf(fmaxf(sp[(2*i)*8 + 2*j], sp[(2*i)*8 + 2*j + 1]),
                     fmaxf(sp[(2*i+1)*8 + 2*j], sp[(2*i+1)*8 + 2*j + 1]));
    sp[64 + t] = mm;
    wsb[pb + 64 + t] = mm;
  }
  __syncthreads();
  if (t < 4) {
    int i = t >> 1, j = t & 1;
    float mm = fmaxf(fmaxf(sp[64 + (2*i)*4 + 2*j], sp[64 + (2*i)*4 + 2*j + 1]),
                     fmaxf(sp[64 + (2*i+1)*4 + 2*j], sp[64 + (2*i+1)*4 + 2*j + 1]));
    sp[80 + t] = mm;
    wsb[pb + 80 + t] = mm;
  }
  __syncthreads();
  if (t == 0)
    wsb[pb + 84] = fmaxf(fmaxf(sp[80], sp[81]), fmaxf(sp[82], sp[83]));
}

// K2: pyramid convs on distinct block values + BN stat accumulation
__global__ __launch_bounds__(256) void k_pyr(const float* __restrict__ wconv, float* __restrict__ wsb) {
  __shared__ __align__(16) float pv[256];
  int bi = blockIdx.x;                       // b*85 + pos
  int b = bi / 85, pos = bi % 85;
  int d = (pos < 64) ? 3 : (pos < 80) ? 2 : (pos < 84) ? 1 : 0;
  int t = threadIdx.x;
  pv[t] = wsb[WS_PALL + (size_t)(b*NCH + t)*POS + pos];
  __syncthreads();
  const float* wrow = wconv + ((size_t)d*NCH + t)*NCH;
  float acc = 0.f;
  #pragma unroll 4
  for (int c4 = 0; c4 < 64; c4++) {
    f32x4 wv = *(const f32x4*)(wrow + c4*4);
    f32x4 xv = *(const f32x4*)(&pv[c4*4]);
    acc += wv.x*xv.x + wv.y*xv.y + wv.z*xv.z + wv.w*xv.w;
  }
  wsb[WS_YD + (size_t)(b*NCH + t)*POS + pos] = acc;
  atomicAdd(&wsb[WS_PSUM + d*NCH + t], acc);
  atomicAdd(&wsb[WS_PSQ  + d*NCH + t], acc*acc);
}

// K3: contrib[b][o][cell] += per-depth partial (grid = d*64 + cell; r5-proven shape)
__global__ __launch_bounds__(256) void k_contrib(const float* __restrict__ wf,
                                                 const float* __restrict__ gs,
                                                 const float* __restrict__ bs,
                                                 float* __restrict__ wsb) {
  __shared__ __align__(16) float pn[4][256];    // [b][c]
  int bi = blockIdx.x;
  int d = bi >> 6, cell = bi & 63;
  int by = cell >> 3, bx = cell & 7;
  int t = threadIdx.x;
  int pos = (d == 3) ? cell
          : (d == 2) ? 64 + (by >> 1)*4 + (bx >> 1)
          : (d == 1) ? 80 + (by >> 2)*2 + (bx >> 2)
          : 84;
  float cnt = (float)(4 << (2*d));
  float mu  = wsb[WS_PSUM + d*NCH + t] / cnt;
  float var = wsb[WS_PSQ  + d*NCH + t] / cnt - mu*mu;
  float sc  = gs[d*NCH + t] * rsqrtf(var + BN_EPS);
  float bi_ = bs[d*NCH + t] - mu * sc;
  #pragma unroll
  for (int b = 0; b < 4; b++)
    pn[b][t] = wsb[WS_YD + (size_t)(b*NCH + t)*POS + pos] * sc + bi_;
  __syncthreads();
  const float* wrow = wf + (size_t)t*1280 + 256 + d*256;
  float a0 = 0.f, a1 = 0.f, a2 = 0.f, a3 = 0.f;
  #pragma unroll 4
  for (int j = 0; j < 64; j++) {
    f32x4 wv = *(const f32x4*)(wrow + j*4);
    f32x4 p0 = *(const f32x4*)(&pn[0][j*4]);
    f32x4 p1 = *(const f32x4*)(&pn[1][j*4]);
    f32x4 p2 = *(const f32x4*)(&pn[2][j*4]);
    f32x4 p3 = *(const f32x4*)(&pn[3][j*4]);
    a0 += wv.x*p0.x + wv.y*p0.y + wv.z*p0.z + wv.w*p0.w;
    a1 += wv.x*p1.x + wv.y*p1.y + wv.z*p1.z + wv.w*p1.w;
    a2 += wv.x*p2.x + wv.y*p2.y + wv.z*p2.z + wv.w*p2.w;
    a3 += wv.x*p3.x + wv.y*p3.y + wv.z*p3.z + wv.w*p3.w;
  }
  atomicAdd(&wsb[WS_CONTRIB + (size_t)(0*NCH + t)*64 + cell], a0);
  atomicAdd(&wsb[WS_CONTRIB + (size_t)(1*NCH + t)*64 + cell], a1);
  atomicAdd(&wsb[WS_CONTRIB + (size_t)(2*NCH + t)*64 + cell], a2);
  atomicAdd(&wsb[WS_CONTRIB + (size_t)(3*NCH + t)*64 + cell], a3);
}

// K4: main GEMM (r9 structure, best measured), 2-slab phases, 4 barriers,
//     LDS union (phase buffers / ytile), r7 coalesced LDS-bounce epilogue.
template<bool YBF>
__global__ __launch_bounds__(256, 3) void k_main(const float* __restrict__ x,
                                                 float* __restrict__ wsb, float* __restrict__ y) {
  __shared__ __align__(16) char smem[40960];     // union: xbuf 2x10240B | ytile 36864B
  __shared__ float ctile[256*4];                 // 4 KB
  u32* xbuf = (u32*)smem;                        // [buf][px*40 u32]
  int wg = blockIdx.x;
  int b = wg / 576, tile = wg % 576;
  int n0 = tile * 64;
  int t = threadIdx.x, w = t >> 6, l = t & 63, g = l >> 4, ln = l & 15;
  int cb0 = (tile % 3) * 64;
  int rowblk = (tile / 3) / 24;
  int cblk0 = cb0 / 24;
  const u16* wpk = (const u16*)(wsb + WS_WPK);
  int mrow = w*64 + ln;
  int qq = t & 15, c2 = t >> 4;                  // staging: px-quad, channel-pair
  const float* xsrc = x + (size_t)(b*NCH + 2*c2)*HW + n0 + 4*qq;

  // ctile global loads (issued first)
  float ct[4];
  {
    const float* cbase = wsb + WS_CONTRIB + ((size_t)b*NCH + t)*64 + rowblk*8;
    #pragma unroll
    for (int i = 0; i < 4; i++) {
      int cc = cblk0 + i; if (cc > 7) cc = 7;
      ct[i] = cbase[cc];
    }
  }
  // prologue: x loads for phases 0,1 (slabs 0..3) -> 8 f32x4 in flight
  f32x4 xr[2][2][2];                             // [phase parity][slab-in-phase][half]
  #pragma unroll
  for (int pp = 0; pp < 2; pp++)
    #pragma unroll
    for (int s = 0; s < 2; s++)
      #pragma unroll
      for (int h = 0; h < 2; h++)
        xr[pp][s][h] = *(const f32x4*)(xsrc + (size_t)((pp*2 + s)*32 + h)*HW);

  #pragma unroll
  for (int i = 0; i < 4; i++) ctile[t*4 + i] = ct[i];
  asm volatile("s_waitcnt lgkmcnt(0)" ::: "memory");
  __builtin_amdgcn_s_barrier();

  f32x4 acc[4][4];
  #pragma unroll
  for (int i = 0; i < 4; i++)
    #pragma unroll
    for (int j = 0; j < 4; j++)
      acc[i][j] = {0.f, 0.f, 0.f, 0.f};

  int slot = (((c2 >> 2) ^ (qq & 3)) << 2) | (c2 & 3);   // group-XOR swizzle

  #pragma unroll
  for (int p = 0; p < 4; p++) {
    // stage phase p (slabs 2p, 2p+1) into buf[p&1]
    {
      u32* dst = xbuf + (p & 1)*2560;
      #pragma unroll
      for (int s = 0; s < 2; s++) {
        f32x4 va = xr[p & 1][s][0], vb = xr[p & 1][s][1];
        #pragma unroll
        for (int j = 0; j < 4; j++) {
          u32 pk = (u32)f2bf(va[j]) | ((u32)f2bf(vb[j]) << 16);
          dst[(4*qq + j)*40 + s*20 + slot] = pk;
        }
      }
    }
    asm volatile("s_waitcnt lgkmcnt(0)" ::: "memory");
    __builtin_amdgcn_s_barrier();
    // prefetch x for phase p+2
    if (p < 2) {
      #pragma unroll
      for (int s = 0; s < 2; s++)
        #pragma unroll
        for (int h = 0; h < 2; h++)
          xr[p & 1][s][h] = *(const f32x4*)(xsrc + (size_t)(((p+2)*2 + s)*32 + h)*HW);
    }
    // compute both slabs of phase p
    #pragma unroll
    for (int s = 0; s < 2; s++) {
      int sl = p*2 + s;
      s16x8 af[4];
      #pragma unroll
      for (int tm = 0; tm < 4; tm++)
        af[tm] = *(const s16x8*)(wpk + ((size_t)(sl*4 + g)*256 + mrow + tm*16)*8);
      const u32* xb = xbuf + (p & 1)*2560 + s*20;
      #pragma unroll
      for (int tn = 0; tn < 4; tn++) {
        int px = 16*tn + ln;
        int gr = g ^ ((px >> 2) & 3);
        s16x8 bfr = *(const s16x8*)((const u16*)&xb[px*40 + gr*4]);
        #pragma unroll
        for (int tm = 0; tm < 4; tm++)
          acc[tm][tn] = __builtin_amdgcn_mfma_f32_16x16x32_bf16(af[tm], bfr, acc[tm][tn], 0, 0, 0);
      }
    }
  }

  // epilogue: add contrib, stats, bf16 into ytile (union: wait for all LDS readers)
  __syncthreads();
  u16* ytile = (u16*)smem;                       // [256 o][72 px pitch]
  int ci[4];
  #pragma unroll
  for (int tn = 0; tn < 4; tn++)
    ci[tn] = (cb0 + 16*tn + ln)/24 - cblk0;
  int bkt = wg & (NBKT - 1);
  float* fsum = wsb + WS_FSUMB + bkt*256;
  float* fsq  = wsb + WS_FSQB  + bkt*256;
  float* yf   = y + (size_t)b*NCH*HW + n0;
  #pragma unroll
  for (int tm = 0; tm < 4; tm++) {
    #pragma unroll
    for (int r = 0; r < 4; r++) {
      int o = w*64 + tm*16 + g*4 + r;
      float s1 = 0.f, s2 = 0.f;
      #pragma unroll
      for (int tn = 0; tn < 4; tn++) {
        int px = 16*tn + ln;
        float v = acc[tm][tn][r] + ctile[o*4 + ci[tn]];
        if (YBF) {
          u16 h = f2bf(v);
          ytile[o*72 + px] = h;
          float yr = bf2f(h);
          s1 += yr; s2 += yr*yr;
        } else {
          yf[(size_t)o*HW + px] = v;
          s1 += v; s2 += v*v;
        }
      }
      s1 += __shfl_xor(s1, 1);  s2 += __shfl_xor(s2, 1);
      s1 += __shfl_xor(s1, 2);  s2 += __shfl_xor(s2, 2);
      s1 += __shfl_xor(s1, 4);  s2 += __shfl_xor(s2, 4);
      s1 += __shfl_xor(s1, 8);  s2 += __shfl_xor(s2, 8);
      if (ln == 0) { atomicAdd(&fsum[o], s1); atomicAdd(&fsq[o], s2); }
    }
  }
  if (YBF) {
    __syncthreads();
    // coalesced store: 8 rounds; lane = (o' = t>>3 within 32-o group, seg = t&7)
    u16* ybb = (u16*)(wsb + WS_YBF) + (size_t)b*NCH*HW + n0;
    int oo = t >> 3, seg = t & 7;
    #pragma unroll
    for (int r8 = 0; r8 < 8; r8++) {
      int o = r8*32 + oo;
      u16x8 v = *(const u16x8*)(&ytile[o*72 + seg*8]);
      *(u16x8*)(ybb + (size_t)o*HW + seg*8) = v;
    }
  }
}

// K5: normalize with inline final BN stats (r2-proven coalesced shape)
template<bool YBF>
__global__ __launch_bounds__(256) void k_norm(float* __restrict__ out,
                                              const float* __restrict__ gf,
                                              const float* __restrict__ bfv,
                                              const float* __restrict__ wsb) {
  int bid = blockIdx.x;                      // plane*4 + quarter
  int plane = bid >> 2, q = bid & 3;
  int c = plane & 255;
  float s1 = 0.f, s2 = 0.f;
  #pragma unroll
  for (int i = 0; i < NBKT; i++) {
    s1 += wsb[WS_FSUMB + i*256 + c];
    s2 += wsb[WS_FSQB  + i*256 + c];
  }
  float inv = 1.f / (float)NPIX;
  float mu  = s1 * inv;
  float var = s2 * inv - mu*mu;
  float sc  = gf[c] * rsqrtf(var + BN_EPS);
  float bi  = bfv[c] - mu * sc;
  size_t base4 = ((size_t)plane*HW + q*(HW/4)) >> 2;   // f32x4 / u16x4 index
  int t = threadIdx.x;
  if (YBF) {
    const u16* yb = (const u16*)(wsb + WS_YBF);
    #pragma unroll
    for (int it = 0; it < 9; it++) {
      size_t i4 = base4 + it*256 + t;
      u16x4 v = *(const u16x4*)(yb + i4*4);
      f32x4 o;
      o.x = bf2f(v[0])*sc + bi;
      o.y = bf2f(v[1])*sc + bi;
      o.z = bf2f(v[2])*sc + bi;
      o.w = bf2f(v[3])*sc + bi;
      ((f32x4*)out)[i4] = o;
    }
  } else {
    #pragma unroll
    for (int it = 0; it < 9; it++) {
      size_t i4 = base4 + it*256 + t;
      f32x4 v = ((f32x4*)out)[i4];
      v.x = v.x*sc + bi; v.y = v.y*sc + bi; v.z = v.z*sc + bi; v.w = v.w*sc + bi;
      ((f32x4*)out)[i4] = v;
    }
  }
}

extern "C" void kernel_launch(void* const* d_in, const int* in_sizes, int n_in,
                              void* d_out, int out_size, void* d_ws, size_t ws_size,
                              hipStream_t stream) {
  const float* x  = (const float*)d_in[0];
  const float* w  = (const float*)d_in[1];
  const float* gs = (const float*)d_in[2];
  const float* bs = (const float*)d_in[3];
  const float* wf = (const float*)d_in[4];
  const float* gf = (const float*)d_in[5];
  const float* bf = (const float*)d_in[6];
  float* y   = (float*)d_out;
  float* wsb = (float*)d_ws;

  bool ybf = ws_size >= (size_t)WS_TOT1 * sizeof(float);

  k_pool   <<<1068, 192, 0, stream>>>(x, wf, wsb);
  k_pyr    <<<NB*POS, 256, 0, stream>>>(w, wsb);
  k_contrib<<<256, 256, 0, stream>>>(wf, gs, bs, wsb);
  if (ybf) k_main<true> <<<NB*576, 256, 0, stream>>>(x, wsb, y);
  else     k_main<false><<<NB*576, 256, 0, stream>>>(x, wsb, y);
  if (ybf) k_norm<true> <<<4096, 256, 0, stream>>>(y, gf, bf, wsb);
  else     k_norm<false><<<4096, 256, 0, stream>>>(y, gf, bf, wsb);
}